// Round 1
// baseline (352.092 us; speedup 1.0000x reference)
//
#include <hip/hip_runtime.h>
#include <hip/hip_bf16.h>
#include <math.h>

typedef __hip_bfloat16 bf16;
typedef __attribute__((ext_vector_type(8))) short bf16x8;
typedef __attribute__((ext_vector_type(4))) float f32x4;

#define MFMA16(a,b,c) __builtin_amdgcn_mfma_f32_16x16x32_bf16((a),(b),(c),0,0,0)

__device__ __forceinline__ void load_lds16(const void* g, void* l) {
  __builtin_amdgcn_global_load_lds(
      (__attribute__((address_space(1))) void*)(g),
      (__attribute__((address_space(3))) void*)(l), 16, 0, 0);
}

// ---------------- fp32 -> bf16 convert ----------------
__global__ void cvt_kernel(const float* __restrict__ in, unsigned short* __restrict__ out, int n4) {
  int i = blockIdx.x * blockDim.x + threadIdx.x;
  if (i >= n4) return;
  float4 v = reinterpret_cast<const float4*>(in)[i];
  bf16 a = __float2bfloat16(v.x), b = __float2bfloat16(v.y);
  bf16 c = __float2bfloat16(v.z), d = __float2bfloat16(v.w);
  ushort4 u;
  u.x = *reinterpret_cast<unsigned short*>(&a);
  u.y = *reinterpret_cast<unsigned short*>(&b);
  u.z = *reinterpret_cast<unsigned short*>(&c);
  u.w = *reinterpret_cast<unsigned short*>(&d);
  reinterpret_cast<ushort4*>(out)[i] = u;
}

// ---------------- bf16 GEMM: C[M,N] = A[M,K] * B[N,K]^T ----------------
// MODE 0: epilogue scatters qkv -> qh[b,h,t,d], kh[b,h,t,d], vt[b,h,d,t] (bf16)
// MODE 1: epilogue stores fp32 to outf[m*1024+n]
template<int MODE>
__global__ __launch_bounds__(256, 2)
void gemm_bt(const bf16* __restrict__ A, const bf16* __restrict__ B,
             bf16* __restrict__ outq, bf16* __restrict__ outk, bf16* __restrict__ outv,
             float* __restrict__ outf, int K) {
  __shared__ __align__(16) bf16 As[128 * 32];
  __shared__ __align__(16) bf16 Bs[128 * 32];
  const int tid = threadIdx.x;
  const int w = tid >> 6;
  const int lane = tid & 63;
  const int quad = lane >> 4;
  const int col = lane & 15;
  const int waveM = w >> 1;
  const int waveN = w & 1;
  const int bm = blockIdx.y * 128;
  const int bn = blockIdx.x * 128;

  f32x4 acc[4][4] = {};

  const int srow = lane >> 2;        // 0..15
  const int skoff = (lane & 3) * 8;  // 0,8,16,24 (bf16 elems)

  for (int k0 = 0; k0 < K; k0 += 32) {
    __syncthreads();
#pragma unroll
    for (int p = 0; p < 2; ++p) {
      int r = p * 64 + w * 16 + srow;
      load_lds16(A + (size_t)(bm + r) * K + k0 + skoff, (char*)As + p * 4096 + w * 1024);
      load_lds16(B + (size_t)(bn + r) * K + k0 + skoff, (char*)Bs + p * 4096 + w * 1024);
    }
    __syncthreads();
    bf16x8 af[4], bfr[4];
#pragma unroll
    for (int i = 0; i < 4; ++i)
      af[i] = *reinterpret_cast<const bf16x8*>(As + (waveM * 64 + i * 16 + col) * 32 + quad * 8);
#pragma unroll
    for (int j = 0; j < 4; ++j)
      bfr[j] = *reinterpret_cast<const bf16x8*>(Bs + (waveN * 64 + j * 16 + col) * 32 + quad * 8);
#pragma unroll
    for (int i = 0; i < 4; ++i)
#pragma unroll
      for (int j = 0; j < 4; ++j)
        acc[i][j] = MFMA16(af[i], bfr[j], acc[i][j]);
  }

#pragma unroll
  for (int i = 0; i < 4; ++i) {
#pragma unroll
    for (int j = 0; j < 4; ++j) {
#pragma unroll
      for (int r = 0; r < 4; ++r) {
        int m = bm + waveM * 64 + i * 16 + quad * 4 + r;  // C row = (lane>>4)*4+reg
        int n = bn + waveN * 64 + j * 16 + col;           // C col = lane&15
        float v = acc[i][j][r];
        if (MODE == 0) {
          int b = m >> 11, t = m & 2047;
          int sel = n >> 10, cc = n & 1023;
          int h = cc >> 6, d = cc & 63;
          int bh = b * 16 + h;
          bf16 bv = __float2bfloat16(v);
          if (sel == 0)      outq[((size_t)bh * 2048 + t) * 64 + d] = bv;
          else if (sel == 1) outk[((size_t)bh * 2048 + t) * 64 + d] = bv;
          else               outv[((size_t)bh * 64 + d) * 2048 + t] = bv;
        } else {
          outf[(size_t)m * 1024 + n] = v;
        }
      }
    }
  }
}

// ---------------- RoPE (in-place on qh, kh; [b,h,t,d] bf16) ----------------
// reference: theta_d = t * base^(-(d mod 32)/32); pair (even d0, d0+1):
//   q'[d0] = q[d0]*cos(th_d0) - q[d0+1]*sin(th_d0)
//   q'[d1] = q[d1]*cos(th_d1) + q[d0]*sin(th_d1)
__global__ void rope_kernel(bf16* __restrict__ qh, bf16* __restrict__ kh) {
  unsigned idx = blockIdx.x * blockDim.x + threadIdx.x;
  bf16* ptr = (idx < (1u << 21)) ? qh : kh;
  unsigned i = idx & ((1u << 21) - 1);
  int p = i & 31;
  int t = (i >> 5) & 2047;
  int bh = i >> 16;
  int d0 = p * 2, d1 = p * 2 + 1;
  float inv0 = 1.0f / powf(10000.0f, (float)(d0 & 31) * (1.0f / 32.0f));
  float inv1 = 1.0f / powf(10000.0f, (float)(d1 & 31) * (1.0f / 32.0f));
  float th0 = (float)t * inv0, th1 = (float)t * inv1;
  float s0, c0, s1, c1;
  sincosf(th0, &s0, &c0);
  sincosf(th1, &s1, &c1);
  size_t base = ((size_t)bh * 2048 + t) * 64;
  float x0 = __bfloat162float(ptr[base + d0]);
  float x1 = __bfloat162float(ptr[base + d1]);
  ptr[base + d0] = __float2bfloat16(x0 * c0 - x1 * s0);
  ptr[base + d1] = __float2bfloat16(x1 * c1 + x0 * s1);
}

// ---------------- flash attention ----------------
// grid (32 qtiles, 32 bh); 256 thr = 4 waves, each wave 16 q rows, 32-key chunks
__global__ __launch_bounds__(256, 2)
void attn_kernel(const bf16* __restrict__ qh, const bf16* __restrict__ kh,
                 const bf16* __restrict__ vt, bf16* __restrict__ y) {
  __shared__ __align__(16) bf16 Ks[32 * 64];   // [key][d]
  __shared__ __align__(16) bf16 Vs[64 * 32];   // [d][key]
  __shared__ __align__(16) bf16 Ps[4][16 * 32];// per-wave [q][key]

  const int bh = blockIdx.y;
  const int w = threadIdx.x >> 6;
  const int lane = threadIdx.x & 63;
  const int quad = lane >> 4;
  const int col = lane & 15;

  const int qrow = blockIdx.x * 64 + w * 16 + col;   // A-frag m = lane&15
  const bf16* qbase = qh + ((size_t)bh * 2048 + qrow) * 64;
  bf16x8 qf0 = *reinterpret_cast<const bf16x8*>(qbase + quad * 8);
  bf16x8 qf1 = *reinterpret_cast<const bf16x8*>(qbase + 32 + quad * 8);

  f32x4 O[4] = {};
  float m_run[4] = {-1e30f, -1e30f, -1e30f, -1e30f};
  float l_run[4] = {};

  const int kkey = w * 8 + (lane >> 3);
  const int kdo  = (lane & 7) * 8;
  const int vd   = w * 16 + (lane >> 2);
  const int vko  = (lane & 3) * 8;
  const bf16* kgb = kh + (size_t)bh * 2048 * 64;
  const bf16* vgb = vt + (size_t)bh * 64 * 2048;

  for (int kc = 0; kc < 2048; kc += 32) {
    __syncthreads();
    load_lds16(kgb + (size_t)(kc + kkey) * 64 + kdo, (char*)Ks + w * 1024);
    load_lds16(vgb + (size_t)vd * 2048 + kc + vko, (char*)Vs + w * 1024);
    __syncthreads();

    // S = Q K^T : two 16-key C-tiles, contraction d=64 in two chained MFMAs
    f32x4 s0 = {}, s1 = {};
    bf16x8 kf;
    kf = *reinterpret_cast<const bf16x8*>(Ks + col * 64 + quad * 8);
    s0 = MFMA16(qf0, kf, s0);
    kf = *reinterpret_cast<const bf16x8*>(Ks + col * 64 + 32 + quad * 8);
    s0 = MFMA16(qf1, kf, s0);
    kf = *reinterpret_cast<const bf16x8*>(Ks + (16 + col) * 64 + quad * 8);
    s1 = MFMA16(qf0, kf, s1);
    kf = *reinterpret_cast<const bf16x8*>(Ks + (16 + col) * 64 + 32 + quad * 8);
    s1 = MFMA16(qf1, kf, s1);

    // online softmax: lane holds rows quad*4+r, keys {col, 16+col}
#pragma unroll
    for (int r = 0; r < 4; ++r) {
      float a = s0[r] * 0.125f, b = s1[r] * 0.125f;
      float mx = fmaxf(a, b);
#pragma unroll
      for (int off = 1; off < 16; off <<= 1)
        mx = fmaxf(mx, __shfl_xor(mx, off, 64));
      float mnew = fmaxf(m_run[r], mx);
      float alpha = __expf(m_run[r] - mnew);
      float p0 = __expf(a - mnew), p1 = __expf(b - mnew);
      float rs = p0 + p1;
#pragma unroll
      for (int off = 1; off < 16; off <<= 1)
        rs += __shfl_xor(rs, off, 64);
      l_run[r] = l_run[r] * alpha + rs;
      m_run[r] = mnew;
      O[0][r] *= alpha; O[1][r] *= alpha; O[2][r] *= alpha; O[3][r] *= alpha;
      Ps[w][(quad * 4 + r) * 32 + col]      = __float2bfloat16(p0);
      Ps[w][(quad * 4 + r) * 32 + 16 + col] = __float2bfloat16(p1);
    }
    __asm__ volatile("s_waitcnt lgkmcnt(0)" ::: "memory");
    // P in A-layout: P[q=lane&15][key=quad*8+j]
    bf16x8 pf = *reinterpret_cast<const bf16x8*>(&Ps[w][col * 32 + quad * 8]);
#pragma unroll
    for (int j = 0; j < 4; ++j) {
      bf16x8 vf = *reinterpret_cast<const bf16x8*>(Vs + (j * 16 + col) * 32 + quad * 8);
      O[j] = MFMA16(pf, vf, O[j]);
    }
  }

  const int b = bh >> 4, h = bh & 15;
#pragma unroll
  for (int r = 0; r < 4; ++r) {
    float inv = 1.0f / l_run[r];
    int t = blockIdx.x * 64 + w * 16 + quad * 4 + r;
    size_t base = ((size_t)b * 2048 + t) * 1024 + h * 64;
#pragma unroll
    for (int j = 0; j < 4; ++j)
      y[base + j * 16 + col] = __float2bfloat16(O[j][r] * inv);
  }
}

extern "C" void kernel_launch(void* const* d_in, const int* in_sizes, int n_in,
                              void* d_out, int out_size, void* d_ws, size_t ws_size,
                              hipStream_t stream) {
  const float* x    = (const float*)d_in[0];
  const float* wqkv = (const float*)d_in[1];
  const float* wout = (const float*)d_in[2];
  float* out = (float*)d_out;
  char* ws = (char*)d_ws;

  bf16* xb    = (bf16*)(ws);
  bf16* wqkvb = (bf16*)(ws + (size_t)(8 << 20));
  bf16* woutb = (bf16*)(ws + (size_t)(14 << 20));
  bf16* qh    = (bf16*)(ws + (size_t)(16 << 20));
  bf16* kh    = (bf16*)(ws + (size_t)(24 << 20));
  bf16* vt    = (bf16*)(ws + (size_t)(32 << 20));
  bf16* y     = (bf16*)(ws + (size_t)(40 << 20));

  cvt_kernel<<<4096, 256, 0, stream>>>(x,    (unsigned short*)xb,    4194304 / 4);
  cvt_kernel<<<3072, 256, 0, stream>>>(wqkv, (unsigned short*)wqkvb, 3145728 / 4);
  cvt_kernel<<<1024, 256, 0, stream>>>(wout, (unsigned short*)woutb, 1048576 / 4);

  gemm_bt<0><<<dim3(24, 32), 256, 0, stream>>>(xb, wqkvb, qh, kh, vt, nullptr, 1024);
  rope_kernel<<<16384, 256, 0, stream>>>(qh, kh);
  attn_kernel<<<dim3(32, 32), 256, 0, stream>>>(qh, kh, vt, y);
  gemm_bt<1><<<dim3(8, 32), 256, 0, stream>>>(y, woutb, nullptr, nullptr, nullptr, out, 1024);
}